// Round 3
// baseline (567.435 us; speedup 1.0000x reference)
//
#include <hip/hip_runtime.h>
#include <hip/hip_bf16.h>
#include <math.h>

// Problem constants
#define B_TOK 4096
#define NE 16
#define DI 1024
#define DH 2048
#define DOUT 1024
#define NSLOT (B_TOK * 2)   // 8192 (token, expert) assignments, exactly

typedef unsigned short u16;
typedef short bfrag __attribute__((ext_vector_type(8)));   // 8 bf16 input frag (4 VGPRs)
typedef float f32x4 __attribute__((ext_vector_type(4)));   // MFMA accumulator
typedef u16 u16x8 __attribute__((ext_vector_type(8)));

// ---------- helpers ----------
__device__ __forceinline__ u16 f2bf(float f) {   // fp32 -> bf16 round-to-nearest-even
    union { float f; unsigned u; } v; v.f = f;
    return (u16)((v.u + 0x7fffu + ((v.u >> 16) & 1u)) >> 16);
}

// async 16B/lane global->LDS. LDS dest must be wave-uniform base (+lane*16 by HW).
__device__ __forceinline__ void async16(const void* g, void* lds) {
    __builtin_amdgcn_global_load_lds(
        (const __attribute__((address_space(1))) void*)g,
        (__attribute__((address_space(3))) void*)lds,
        16, 0, 0);
}

// ---------- kernel 0: zero output ----------
__global__ void zero_init(float* __restrict__ out, int n4) {
    int i = blockIdx.x * blockDim.x + threadIdx.x;
    if (i < n4) ((float4*)out)[i] = make_float4(0.f, 0.f, 0.f, 0.f);
}

// ---------- kernel 1: fp32 -> bf16 convert, 8 elems/thread ----------
__global__ void convert_bf16(const float* __restrict__ src, u16* __restrict__ dst, int n8) {
    int i = blockIdx.x * blockDim.x + threadIdx.x;
    if (i >= n8) return;
    const float4* s4 = (const float4*)src;
    float4 a = s4[2 * i], b = s4[2 * i + 1];
    u16x8 r;
    r[0] = f2bf(a.x); r[1] = f2bf(a.y); r[2] = f2bf(a.z); r[3] = f2bf(a.w);
    r[4] = f2bf(b.x); r[5] = f2bf(b.y); r[6] = f2bf(b.z); r[7] = f2bf(b.w);
    ((u16x8*)dst)[i] = r;
}

// ---------- kernel 2: gating (fp64 dots for exact top-k ordering; NO global atomics) ----------
__global__ __launch_bounds__(256) void gate_topk(
    const float* __restrict__ x, const float* __restrict__ gw,
    int* __restrict__ token_e, float* __restrict__ token_w)
{
    int wave = threadIdx.x >> 6, lane = threadIdx.x & 63;
    int t = blockIdx.x * 4 + wave;            // grid 1024 * 4 waves = 4096 tokens
    const float4* x4 = (const float4*)(x + (size_t)t * DI);
    const float4* g4 = (const float4*)gw;
    double acc[NE];
#pragma unroll
    for (int e = 0; e < NE; ++e) acc[e] = 0.0;
#pragma unroll
    for (int i = 0; i < 4; ++i) {
        float4 xv = x4[lane + i * 64];
#pragma unroll
        for (int e = 0; e < NE; ++e) {
            float4 gv = g4[e * 256 + lane + i * 64];
            acc[e] += (double)xv.x * gv.x + (double)xv.y * gv.y
                    + (double)xv.z * gv.z + (double)xv.w * gv.w;
        }
    }
#pragma unroll
    for (int e = 0; e < NE; ++e) {
        double v = acc[e];
        for (int off = 32; off; off >>= 1) v += __shfl_xor(v, off, 64);
        acc[e] = v;
    }
    if (lane == 0) {
        int e0 = 0; double v0 = acc[0];
#pragma unroll
        for (int e = 1; e < NE; ++e) if (acc[e] > v0) { v0 = acc[e]; e0 = e; }
        int e1 = -1; double v1 = -1e300;
#pragma unroll
        for (int e = 0; e < NE; ++e) if (e != e0 && acc[e] > v1) { v1 = acc[e]; e1 = e; }
        float d = expf((float)(v1 - v0));        // v1 <= v0, d in (0,1]
        float w0 = 1.f / (1.f + d);
        float w1 = d * w0;
        token_e[2 * t] = e0; token_e[2 * t + 1] = e1;
        token_w[2 * t] = w0; token_w[2 * t + 1] = w1;
    }
}

// ---------- kernel 3: routing — histogram + scan + slot fill, one block, LDS atomics ----------
__global__ __launch_bounds__(1024) void route(
    const int* __restrict__ token_e, const float* __restrict__ token_w,
    int* __restrict__ counts, int* __restrict__ offsets,
    int* __restrict__ slot_token, float* __restrict__ slot_wgt)
{
    __shared__ int lcnt[NE];
    __shared__ int lcur[NE];
    int tid = threadIdx.x;
    if (tid < NE) lcnt[tid] = 0;
    __syncthreads();
    for (int i = tid; i < NSLOT; i += 1024) atomicAdd(&lcnt[token_e[i]], 1);
    __syncthreads();
    if (tid == 0) {
        int s = 0;
        for (int e = 0; e < NE; ++e) {
            int c = lcnt[e];
            counts[e] = c; offsets[e] = s; lcur[e] = s; s += c;
        }
    }
    __syncthreads();
    for (int i = tid; i < NSLOT; i += 1024) {
        int e = token_e[i];
        int pos = atomicAdd(&lcur[e], 1);
        slot_token[pos] = i >> 1;
        slot_wgt[pos] = token_w[i];
    }
}

// ---------- grouped GEMM: 128x128 tile, BK=64, 4 waves (2x2), 16x16x32 bf16 MFMA ----------
// LDS: A [128][64] + B [128][64] u16, XOR chunk swizzle: LDS[row][c] holds
// global chunk (c ^ (row&7)); read of chunk g at LDS chunk g ^ (mr&7) ->
// 2-way bank aliasing only (free per m136).
// PHASE 1: h = relu(x_sel @ w1[e]^T + b1[e]) -> hb (bf16)
// PHASE 2: out[token] += wgt * (h @ w2[e]^T + b2[e])  (fp32 atomics)
template <int PHASE>
__global__ __launch_bounds__(256) void moe_gemm(
    const u16* __restrict__ Abuf,   // PHASE1: xb [4096][1024]; PHASE2: hb [8192][2048]
    const u16* __restrict__ Bbuf,   // bf16 weights: [NE][NDIM][KDIM] (K contiguous)
    const float* __restrict__ bias, // [NE][NDIM] fp32
    const int* __restrict__ counts, const int* __restrict__ offsets,
    const int* __restrict__ slot_token, const float* __restrict__ slot_wgt,
    u16* __restrict__ hb, float* __restrict__ out)
{
    constexpr int KDIM = (PHASE == 1) ? DI : DH;
    constexpr int NDIM = (PHASE == 1) ? DH : DOUT;

    const int e = blockIdx.z;
    const int cnt = counts[e];
    const int m0 = blockIdx.y * 128;
    if (m0 >= cnt) return;                    // wave-uniform early exit
    const int n0 = blockIdx.x * 128;
    const int sbase = offsets[e];

    __shared__ u16 ldsbuf[16384];             // 32 KB: A [128][64] | B [128][64]
    u16* alds = ldsbuf;
    u16* blds = ldsbuf + 8192;

    const int tid = threadIdx.x;
    const int wv = tid >> 6, lane = tid & 63;
    const int lrow = lane >> 3;               // 0..7 (row within 8-row group)
    const int lkc = lane & 7;                 // 16B chunk within 8-chunk row
    const int skc = lkc ^ lrow;               // swizzled global source chunk

    // staging pointers: round r covers rows r*32 + wv*8 + lrow
    const u16* aptr[4]; const u16* bptr[4];
    const u16* bbase = Bbuf + (size_t)e * NDIM * KDIM;
#pragma unroll
    for (int r = 0; r < 4; ++r) {
        int arow = m0 + r * 32 + wv * 8 + lrow;
        if (PHASE == 1) {
            int c = cnt - 1; if (arow > c) arow = c;
            aptr[r] = Abuf + (size_t)slot_token[sbase + arow] * KDIM + skc * 8;
        } else {
            int s = sbase + arow; if (s > NSLOT - 1) s = NSLOT - 1;
            aptr[r] = Abuf + (size_t)s * KDIM + skc * 8;
        }
        int brow = n0 + r * 32 + wv * 8 + lrow;
        bptr[r] = bbase + (size_t)brow * KDIM + skc * 8;
    }

    f32x4 acc[4][4];
#pragma unroll
    for (int i = 0; i < 4; ++i)
#pragma unroll
        for (int j = 0; j < 4; ++j) acc[i][j] = (f32x4){0.f, 0.f, 0.f, 0.f};

    const int wm = (wv & 1) * 64, wn = (wv >> 1) * 64;   // 2x2 wave grid, 64x64 per wave
    const int quad = lane >> 4, mr = lane & 15;
    const int msw = mr & 7;                   // read-side swizzle key

    const int nk = KDIM / 64;
    for (int kt = 0; kt < nk; ++kt) {
        __syncthreads();                       // prev tile fully consumed
#pragma unroll
        for (int r = 0; r < 4; ++r) {
            async16(aptr[r] + kt * 64, alds + (r * 32 + wv * 8) * 64);
            async16(bptr[r] + kt * 64, blds + (r * 32 + wv * 8) * 64);
        }
        __syncthreads();                       // vmcnt(0) drain -> tile visible
#pragma unroll
        for (int kk = 0; kk < 2; ++kk) {
            bfrag af[4], bf[4];
            const int ch = ((kk * 4 + quad) ^ msw) * 8;
#pragma unroll
            for (int i = 0; i < 4; ++i) af[i] = *(const bfrag*)(alds + (wm + i * 16 + mr) * 64 + ch);
#pragma unroll
            for (int j = 0; j < 4; ++j) bf[j] = *(const bfrag*)(blds + (wn + j * 16 + mr) * 64 + ch);
#pragma unroll
            for (int i = 0; i < 4; ++i)
#pragma unroll
                for (int j = 0; j < 4; ++j)
                    acc[i][j] = __builtin_amdgcn_mfma_f32_16x16x32_bf16(af[i], bf[j], acc[i][j], 0, 0, 0);
        }
    }

    // epilogue. C/D layout: n = lane&15, m = quad*4 + reg  [m89-verified]
    const float* bias_e = bias + e * NDIM;
    if constexpr (PHASE == 1) {
#pragma unroll
        for (int i = 0; i < 4; ++i) {
            int mbase = wm + i * 16 + quad * 4;
#pragma unroll
            for (int j = 0; j < 4; ++j) {
                int n = n0 + wn + j * 16 + mr;
                float bv = bias_e[n];
#pragma unroll
                for (int r = 0; r < 4; ++r) {
                    int m = m0 + mbase + r;
                    if (m < cnt) {
                        float v = acc[i][j][r] + bv;
                        v = v > 0.f ? v : 0.f;
                        hb[(size_t)(sbase + m) * DH + n] = f2bf(v);
                    }
                }
            }
        }
    } else {
#pragma unroll
        for (int i = 0; i < 4; ++i) {
            int mbase = wm + i * 16 + quad * 4;
#pragma unroll
            for (int r = 0; r < 4; ++r) {
                int m = m0 + mbase + r;
                if (m < cnt) {
                    int slot = sbase + m;
                    int tok = slot_token[slot];
                    float wgt = slot_wgt[slot];
                    float* orow = out + (size_t)tok * DOUT + n0 + wn;
#pragma unroll
                    for (int j = 0; j < 4; ++j) {
                        int nl = j * 16 + mr;
                        float v = wgt * (acc[i][j][r] + bias_e[n0 + wn + nl]);
                        atomicAdd(orow + nl, v);
                    }
                }
            }
        }
    }
}

// ---------- launch ----------
extern "C" void kernel_launch(void* const* d_in, const int* in_sizes, int n_in,
                              void* d_out, int out_size, void* d_ws, size_t ws_size,
                              hipStream_t stream) {
    const float* x  = (const float*)d_in[0];   // [4096][1024]
    const float* gw = (const float*)d_in[1];   // [16][1024]
    const float* w1 = (const float*)d_in[2];   // [16][2048][1024]
    const float* b1 = (const float*)d_in[3];   // [16][2048]
    const float* w2 = (const float*)d_in[4];   // [16][1024][2048]
    const float* b2 = (const float*)d_in[5];   // [16][1024]
    float* out = (float*)d_out;                // [4096][1024] fp32

    // workspace layout (~104.1 MiB)
    char* ws = (char*)d_ws;
    u16* xb = (u16*)ws;                                   //  8,388,608 B
    u16* wb = (u16*)(ws + 8388608);                       // 67,108,864 B (w1 then reused for w2)
    u16* hb = (u16*)(ws + 8388608 + 67108864);            // 33,554,432 B
    char* rb = ws + 109051904;
    int*   counts     = (int*)(rb);
    int*   offsets    = (int*)(rb + 64);
    int*   token_e    = (int*)(rb + 192);
    float* token_w    = (float*)(rb + 192 + 32768);
    int*   slot_token = (int*)(rb + 192 + 65536);
    float* slot_wgt   = (float*)(rb + 192 + 98304);

    zero_init<<<4096, 256, 0, stream>>>(out, (B_TOK * DOUT) / 4);
    convert_bf16<<<2048, 256, 0, stream>>>(x, xb, (B_TOK * DI) / 8);
    convert_bf16<<<16384, 256, 0, stream>>>(w1, wb, (NE * DH * DI) / 8);
    gate_topk<<<1024, 256, 0, stream>>>(x, gw, token_e, token_w);
    route<<<1, 1024, 0, stream>>>(token_e, token_w, counts, offsets, slot_token, slot_wgt);
    moe_gemm<1><<<dim3(DH / 128, B_TOK / 128, NE), 256, 0, stream>>>(
        xb, wb, b1, counts, offsets, slot_token, slot_wgt, hb, out);
    convert_bf16<<<16384, 256, 0, stream>>>(w2, wb, (NE * DOUT * DH) / 8);
    moe_gemm<2><<<dim3(DOUT / 128, B_TOK / 128, NE), 256, 0, stream>>>(
        hb, wb, b2, counts, offsets, slot_token, slot_wgt, hb, out);
}

// Round 4
// 515.610 us; speedup vs baseline: 1.1005x; 1.1005x over previous
//
#include <hip/hip_runtime.h>
#include <hip/hip_bf16.h>
#include <math.h>

// Problem constants
#define B_TOK 4096
#define NE 16
#define DI 1024
#define DH 2048
#define DOUT 1024
#define NSLOT (B_TOK * 2)   // 8192 (token, expert) assignments, exactly

typedef unsigned short u16;
typedef short bfrag __attribute__((ext_vector_type(8)));   // 8 bf16 input frag (4 VGPRs)
typedef float f32x4 __attribute__((ext_vector_type(4)));   // MFMA accumulator
typedef u16 u16x8 __attribute__((ext_vector_type(8)));

// ---------- helpers ----------
__device__ __forceinline__ u16 f2bf(float f) {   // fp32 -> bf16 round-to-nearest-even
    union { float f; unsigned u; } v; v.f = f;
    return (u16)((v.u + 0x7fffu + ((v.u >> 16) & 1u)) >> 16);
}

// async 16B/lane global->LDS. LDS dest must be wave-uniform base (+lane*16 by HW).
__device__ __forceinline__ void async16(const void* g, void* lds) {
    __builtin_amdgcn_global_load_lds(
        (const __attribute__((address_space(1))) void*)g,
        (__attribute__((address_space(3))) void*)lds,
        16, 0, 0);
}

// ---------- kernel 0: zero output ----------
__global__ void zero_init(float* __restrict__ out, int n4) {
    int i = blockIdx.x * blockDim.x + threadIdx.x;
    if (i < n4) ((float4*)out)[i] = make_float4(0.f, 0.f, 0.f, 0.f);
}

// ---------- kernel 1: fp32 -> bf16 convert, 8 elems/thread ----------
__global__ void convert_bf16(const float* __restrict__ src, u16* __restrict__ dst, int n8) {
    int i = blockIdx.x * blockDim.x + threadIdx.x;
    if (i >= n8) return;
    const float4* s4 = (const float4*)src;
    float4 a = s4[2 * i], b = s4[2 * i + 1];
    u16x8 r;
    r[0] = f2bf(a.x); r[1] = f2bf(a.y); r[2] = f2bf(a.z); r[3] = f2bf(a.w);
    r[4] = f2bf(b.x); r[5] = f2bf(b.y); r[6] = f2bf(b.z); r[7] = f2bf(b.w);
    ((u16x8*)dst)[i] = r;
}

// ---------- kernel 2: gating (fp64 dots for exact top-k ordering) + x->bf16 fused ----------
__global__ __launch_bounds__(256) void gate_topk(
    const float* __restrict__ x, const float* __restrict__ gw,
    int* __restrict__ token_e, float* __restrict__ token_w, u16* __restrict__ xb)
{
    int wave = threadIdx.x >> 6, lane = threadIdx.x & 63;
    int t = blockIdx.x * 4 + wave;            // grid 1024 * 4 waves = 4096 tokens
    const float4* x4 = (const float4*)(x + (size_t)t * DI);
    const float4* g4 = (const float4*)gw;
    ushort4* xb4 = (ushort4*)(xb + (size_t)t * DI);
    double acc[NE];
#pragma unroll
    for (int e = 0; e < NE; ++e) acc[e] = 0.0;
#pragma unroll
    for (int i = 0; i < 4; ++i) {
        float4 xv = x4[lane + i * 64];
        ushort4 c; c.x = f2bf(xv.x); c.y = f2bf(xv.y); c.z = f2bf(xv.z); c.w = f2bf(xv.w);
        xb4[lane + i * 64] = c;               // fused x->bf16 (coalesced 8B stores)
#pragma unroll
        for (int e = 0; e < NE; ++e) {
            float4 gv = g4[e * 256 + lane + i * 64];
            acc[e] += (double)xv.x * gv.x + (double)xv.y * gv.y
                    + (double)xv.z * gv.z + (double)xv.w * gv.w;
        }
    }
#pragma unroll
    for (int e = 0; e < NE; ++e) {
        double v = acc[e];
        for (int off = 32; off; off >>= 1) v += __shfl_xor(v, off, 64);
        acc[e] = v;
    }
    if (lane == 0) {
        int e0 = 0; double v0 = acc[0];
#pragma unroll
        for (int e = 1; e < NE; ++e) if (acc[e] > v0) { v0 = acc[e]; e0 = e; }
        int e1 = -1; double v1 = -1e300;
#pragma unroll
        for (int e = 0; e < NE; ++e) if (e != e0 && acc[e] > v1) { v1 = acc[e]; e1 = e; }
        float d = expf((float)(v1 - v0));        // v1 <= v0, d in (0,1]
        float w0 = 1.f / (1.f + d);
        float w1 = d * w0;
        token_e[2 * t] = e0; token_e[2 * t + 1] = e1;
        token_w[2 * t] = w0; token_w[2 * t + 1] = w1;
    }
}

// ---------- kernel 3: routing — histogram + scan + slot fill, one block, LDS atomics ----------
__global__ __launch_bounds__(1024) void route(
    const int* __restrict__ token_e, const float* __restrict__ token_w,
    int* __restrict__ counts, int* __restrict__ offsets,
    int* __restrict__ slot_token, float* __restrict__ slot_wgt)
{
    __shared__ int lcnt[NE];
    __shared__ int lcur[NE];
    int tid = threadIdx.x;
    if (tid < NE) lcnt[tid] = 0;
    __syncthreads();
    for (int i = tid; i < NSLOT; i += 1024) atomicAdd(&lcnt[token_e[i]], 1);
    __syncthreads();
    if (tid == 0) {
        int s = 0;
        for (int e = 0; e < NE; ++e) {
            int c = lcnt[e];
            counts[e] = c; offsets[e] = s; lcur[e] = s; s += c;
        }
    }
    __syncthreads();
    for (int i = tid; i < NSLOT; i += 1024) {
        int e = token_e[i];
        int pos = atomicAdd(&lcur[e], 1);
        slot_token[pos] = i >> 1;
        slot_wgt[pos] = token_w[i];
    }
}

// ---------- grouped GEMM: 128x128 tile, BK=32, 4 waves (2x2), 16x16x32 bf16 MFMA ----------
// 3-stage LDS pipeline (16 KB/stage): prefetch tiles k+1,k+2 via global_load_lds;
// K-loop barrier is raw s_barrier + s_waitcnt vmcnt(4) so prefetch stays in flight
// (never vmcnt(0) inside the loop — the AITER-style structure, m139 mechanism).
// XOR swizzle: LDS[row][p] holds global chunk p ^ ((row>>1)&3); 16-lane b128 read
// covers each bank exactly 2x -> conflict-free (m136: 2-way is free).
// PHASE 1: h = relu(x_sel @ w1[e]^T + b1[e]) -> hb (bf16)
// PHASE 2: out[token] += wgt * (h @ w2[e]^T + b2[e])  (fp32 atomics)
template <int PHASE>
__global__ __launch_bounds__(256) void moe_gemm(
    const u16* __restrict__ Abuf,   // PHASE1: xb [4096][1024]; PHASE2: hb [8192][2048]
    const u16* __restrict__ Bbuf,   // bf16 weights: [NE][NDIM][KDIM] (K contiguous)
    const float* __restrict__ bias, // [NE][NDIM] fp32
    const int* __restrict__ counts, const int* __restrict__ offsets,
    const int* __restrict__ slot_token, const float* __restrict__ slot_wgt,
    u16* __restrict__ hb, float* __restrict__ out)
{
    constexpr int KDIM = (PHASE == 1) ? DI : DH;
    constexpr int NDIM = (PHASE == 1) ? DH : DOUT;
    constexpr int nk = KDIM / 32;

    const int e = blockIdx.z;
    const int cnt = counts[e];
    const int m0 = blockIdx.y * 128;
    if (m0 >= cnt) return;                    // block-uniform early exit
    const int n0 = blockIdx.x * 128;
    const int sbase = offsets[e];

    __shared__ u16 ldsbuf[3 * 8192];          // 48 KB: 3 stages x (A[128][32] | B[128][32])

    const int tid = threadIdx.x;
    const int wv = tid >> 6, lane = tid & 63;
    const int lrow = lane >> 2;               // 0..15 staging row within 16-row slab
    const int lkc = lane & 3;                 // 16B chunk within 4-chunk (64B) row
    const int skc = lkc ^ ((lrow >> 1) & 3);  // swizzled global source chunk

    // staging pointers: round rd covers rows rd*64 + wv*16 + lrow
    const u16* aptr[2]; const u16* bptr[2];
    const u16* bbase = Bbuf + (size_t)e * NDIM * KDIM;
#pragma unroll
    for (int rd = 0; rd < 2; ++rd) {
        int arow = m0 + rd * 64 + wv * 16 + lrow;
        if (PHASE == 1) {
            int c = cnt - 1; if (arow > c) arow = c;
            aptr[rd] = Abuf + (size_t)slot_token[sbase + arow] * KDIM + skc * 8;
        } else {
            int s = sbase + arow; if (s > NSLOT - 1) s = NSLOT - 1;
            aptr[rd] = Abuf + (size_t)s * KDIM + skc * 8;
        }
        int brow = n0 + rd * 64 + wv * 16 + lrow;
        bptr[rd] = bbase + (size_t)brow * KDIM + skc * 8;
    }
    const int slab0 = wv * 512;               // rd=0 LDS slab (u16 units)
    const int slab1 = 2048 + wv * 512;        // rd=1

    f32x4 acc[4][4];
#pragma unroll
    for (int i = 0; i < 4; ++i)
#pragma unroll
        for (int j = 0; j < 4; ++j) acc[i][j] = (f32x4){0.f, 0.f, 0.f, 0.f};

    const int wm = (wv & 1) * 64, wn = (wv >> 1) * 64;   // 2x2 wave grid, 64x64 per wave
    const int quad = lane >> 4, mr = lane & 15;
    const int ach = (quad ^ ((mr >> 1) & 3)) * 8;        // swizzled read chunk (u16)
    const int aro = (wm + mr) * 32 + ach;
    const int bro = 4096 + (wn + mr) * 32 + ach;

    // prologue: fill stages 0 and 1 (8 async16/lane outstanding)
#pragma unroll
    for (int p = 0; p < 2; ++p) {
        u16* base = ldsbuf + p * 8192;
        async16(aptr[0] + p * 32, base + slab0);
        async16(aptr[1] + p * 32, base + slab1);
        async16(bptr[0] + p * 32, base + 4096 + slab0);
        async16(bptr[1] + p * 32, base + 4096 + slab1);
    }

    int cb = 0;                               // stage holding tile k
    for (int k = 0; k < nk; ++k) {
        // wait: 4 oldest loads (tile k) done; keep tile k+1's 4 in flight
        if (k + 1 < nk) __builtin_amdgcn_s_waitcnt(0x0F74);  // vmcnt(4)
        else            __builtin_amdgcn_s_waitcnt(0x0F70);  // vmcnt(0)
        __builtin_amdgcn_s_barrier();         // all waves' tile-k loads visible;
                                              // all waves done reading stage (k+2)%3
        if (k + 2 < nk) {
            int nb = cb + 2; if (nb >= 3) nb -= 3;
            u16* base = ldsbuf + nb * 8192;
            async16(aptr[0] + (k + 2) * 32, base + slab0);
            async16(aptr[1] + (k + 2) * 32, base + slab1);
            async16(bptr[0] + (k + 2) * 32, base + 4096 + slab0);
            async16(bptr[1] + (k + 2) * 32, base + 4096 + slab1);
        }
        const u16* sb = ldsbuf + cb * 8192;
        bfrag af[4], bf[4];
#pragma unroll
        for (int i = 0; i < 4; ++i) af[i] = *(const bfrag*)(sb + aro + i * 512);
#pragma unroll
        for (int j = 0; j < 4; ++j) bf[j] = *(const bfrag*)(sb + bro + j * 512);
#pragma unroll
        for (int i = 0; i < 4; ++i)
#pragma unroll
            for (int j = 0; j < 4; ++j)
                acc[i][j] = __builtin_amdgcn_mfma_f32_16x16x32_bf16(af[i], bf[j], acc[i][j], 0, 0, 0);
        if (++cb == 3) cb = 0;
    }

    // epilogue. C/D layout: n = lane&15, m = quad*4 + reg  [m89-verified]
    const float* bias_e = bias + e * NDIM;
    if constexpr (PHASE == 1) {
#pragma unroll
        for (int i = 0; i < 4; ++i) {
            int mbase = wm + i * 16 + quad * 4;
#pragma unroll
            for (int j = 0; j < 4; ++j) {
                int n = n0 + wn + j * 16 + mr;
                float bv = bias_e[n];
#pragma unroll
                for (int r = 0; r < 4; ++r) {
                    int m = m0 + mbase + r;
                    if (m < cnt) {
                        float v = acc[i][j][r] + bv;
                        v = v > 0.f ? v : 0.f;
                        hb[(size_t)(sbase + m) * DH + n] = f2bf(v);
                    }
                }
            }
        }
    } else {
#pragma unroll
        for (int i = 0; i < 4; ++i) {
            int mbase = wm + i * 16 + quad * 4;
#pragma unroll
            for (int r = 0; r < 4; ++r) {
                int m = m0 + mbase + r;
                if (m < cnt) {
                    int slot = sbase + m;
                    int tok = slot_token[slot];
                    float wgt = slot_wgt[slot];
                    float* orow = out + (size_t)tok * DOUT + n0 + wn;
#pragma unroll
                    for (int j = 0; j < 4; ++j) {
                        int nl = j * 16 + mr;
                        float v = wgt * (acc[i][j][r] + bias_e[n0 + wn + nl]);
                        atomicAdd(orow + nl, v);
                    }
                }
            }
        }
    }
}

// ---------- launch ----------
extern "C" void kernel_launch(void* const* d_in, const int* in_sizes, int n_in,
                              void* d_out, int out_size, void* d_ws, size_t ws_size,
                              hipStream_t stream) {
    const float* x  = (const float*)d_in[0];   // [4096][1024]
    const float* gw = (const float*)d_in[1];   // [16][1024]
    const float* w1 = (const float*)d_in[2];   // [16][2048][1024]
    const float* b1 = (const float*)d_in[3];   // [16][2048]
    const float* w2 = (const float*)d_in[4];   // [16][1024][2048]
    const float* b2 = (const float*)d_in[5];   // [16][1024]
    float* out = (float*)d_out;                // [4096][1024] fp32

    // workspace layout (~104.1 MiB)
    char* ws = (char*)d_ws;
    u16* xb = (u16*)ws;                                   //  8,388,608 B
    u16* wb = (u16*)(ws + 8388608);                       // 67,108,864 B (w1 then reused for w2)
    u16* hb = (u16*)(ws + 8388608 + 67108864);            // 33,554,432 B
    char* rb = ws + 109051904;
    int*   counts     = (int*)(rb);
    int*   offsets    = (int*)(rb + 64);
    int*   token_e    = (int*)(rb + 192);
    float* token_w    = (float*)(rb + 192 + 32768);
    int*   slot_token = (int*)(rb + 192 + 65536);
    float* slot_wgt   = (float*)(rb + 192 + 98304);

    zero_init<<<4096, 256, 0, stream>>>(out, (B_TOK * DOUT) / 4);
    gate_topk<<<1024, 256, 0, stream>>>(x, gw, token_e, token_w, xb);
    convert_bf16<<<16384, 256, 0, stream>>>(w1, wb, (NE * DH * DI) / 8);
    route<<<1, 1024, 0, stream>>>(token_e, token_w, counts, offsets, slot_token, slot_wgt);
    moe_gemm<1><<<dim3(DH / 128, B_TOK / 128, NE), 256, 0, stream>>>(
        xb, wb, b1, counts, offsets, slot_token, slot_wgt, hb, out);
    convert_bf16<<<16384, 256, 0, stream>>>(w2, wb, (NE * DOUT * DH) / 8);
    moe_gemm<2><<<dim3(DOUT / 128, B_TOK / 128, NE), 256, 0, stream>>>(
        hb, wb, b2, counts, offsets, slot_token, slot_wgt, hb, out);
}